// Round 1
// baseline (988.596 us; speedup 1.0000x reference)
//
#include <hip/hip_runtime.h>
#include <math.h>

#define BLOCK 256
#define BR 8        // rows per block
#define DD 1024     // state dimension
#define RR 64       // rank
#define NW 4        // waves per block

// block LDS: 2*BR*DD*4 (x,v) + 2*BR*RR*4 (q,p) + small = ~68.2 KB -> 2 blocks/CU
__global__ __launch_bounds__(BLOCK, 2)
void yoshida_kernel(const float* __restrict__ x_in, const float* __restrict__ v_in,
                    const float* __restrict__ force, const float* __restrict__ U,
                    const float* __restrict__ Wm, const float* __restrict__ Vw,
                    const int* __restrict__ steps_p, float* __restrict__ out,
                    long vout_off)
{
    __shared__ float xs[BR][DD];
    __shared__ float vs[BR][DD];
    __shared__ float qacc[BR][RR];
    __shared__ float pacc[BR][RR];
    __shared__ float xpart[NW][BR];
    __shared__ float sing[BR];

    const int tid  = threadIdx.x;
    const int wave = tid >> 6;
    const int lane = tid & 63;
    const long row0 = (long)blockIdx.x * BR;

    float4* xs4 = (float4*)&xs[0][0];
    float4* vs4 = (float4*)&vs[0][0];

    // ---- load state rows into LDS (coalesced float4) ----
    {
        const float4* xg = (const float4*)(x_in + row0 * DD);
        const float4* vg = (const float4*)(v_in + row0 * DD);
#pragma unroll
        for (int i = 0; i < (BR*DD/4)/BLOCK; ++i) {
            xs4[tid + i*BLOCK] = xg[tid + i*BLOCK];
            vs4[tid + i*BLOCK] = vg[tid + i*BLOCK];
        }
    }
    const int nsteps = steps_p[0];
    __syncthreads();

    // Yoshida coefficients (double -> float, matches Python-side constants)
    const double W1 = 1.35120719195965763;
    const double W0 = -1.70241438391931527;
    const double dtd = 0.01;                 // DT * DT_SCALE
    const float c1 = (float)(0.5*W1*dtd);         // C1*dt == C4*dt
    const float c2 = (float)(0.5*(W0+W1)*dtd);    // C2*dt == C3*dt
    const float d1 = (float)(W1*dtd);             // D1*dt == D3*dt
    const float d2 = (float)(W0*dtd);             // D2*dt

    auto substep = [&](const float cdtk, const float ddtk) {
        // ---------- Phase X: x += c*dt*v ; per-row ||x||^2 partials; zero q/p acc ----------
        float part[BR];
#pragma unroll
        for (int i = 0; i < BR; ++i) {
            float4 xv = xs4[tid + i*BLOCK];           // float4 index tid+256*i lies in row i
            const float4 vv = vs4[tid + i*BLOCK];
            xv.x = fmaf(cdtk, vv.x, xv.x);
            xv.y = fmaf(cdtk, vv.y, xv.y);
            xv.z = fmaf(cdtk, vv.z, xv.z);
            xv.w = fmaf(cdtk, vv.w, xv.w);
            xs4[tid + i*BLOCK] = xv;
            part[i] = fmaf(xv.x, xv.x, fmaf(xv.y, xv.y, fmaf(xv.z, xv.z, xv.w*xv.w)));
        }
#pragma unroll
        for (int i = 0; i < BR; ++i) {
            float p = part[i];
#pragma unroll
            for (int off = 32; off > 0; off >>= 1) p += __shfl_xor(p, off);
            if (lane == 0) xpart[wave][i] = p;
        }
#pragma unroll
        for (int i = 0; i < (BR*RR)/BLOCK; ++i) {
            (&qacc[0][0])[tid + i*BLOCK] = 0.0f;
            (&pacc[0][0])[tid + i*BLOCK] = 0.0f;
        }
        __syncthreads();

        if (tid < BR) {
            const float xn2 = xpart[0][tid] + xpart[1][tid] + xpart[2][tid] + xpart[3][tid];
            sing[tid] = 1.0f + 20.0f * expf(-xn2 / 10.0f);
        }

        // ---------- Phase Q: q = v@U, p = x@V_w (lane<->rank, wave<->d-quarter) ----------
        float qa[BR], pa[BR];
#pragma unroll
        for (int i = 0; i < BR; ++i) { qa[i] = 0.0f; pa[i] = 0.0f; }
        {
            const int dbase = wave * (DD/NW);
            const float* __restrict__ Up = U  + (long)dbase * RR + lane;
            const float* __restrict__ Vp = Vw + (long)dbase * RR + lane;
#pragma unroll 2
            for (int it = 0; it < (DD/NW)/4; ++it) {
                const float u0 = Up[it*4*RR];
                const float u1 = Up[it*4*RR +   RR];
                const float u2 = Up[it*4*RR + 2*RR];
                const float u3 = Up[it*4*RR + 3*RR];
                const float t0 = Vp[it*4*RR];
                const float t1 = Vp[it*4*RR +   RR];
                const float t2 = Vp[it*4*RR + 2*RR];
                const float t3 = Vp[it*4*RR + 3*RR];
                const int d0 = dbase + it*4;
#pragma unroll
                for (int i = 0; i < BR; ++i) {
                    const float4 v4 = *(const float4*)&vs[i][d0];   // uniform (broadcast) b128
                    const float4 x4 = *(const float4*)&xs[i][d0];
                    qa[i] = fmaf(v4.w, u3, fmaf(v4.z, u2, fmaf(v4.y, u1, fmaf(v4.x, u0, qa[i]))));
                    pa[i] = fmaf(x4.w, t3, fmaf(x4.z, t2, fmaf(x4.y, t1, fmaf(x4.x, t0, pa[i]))));
                }
            }
        }
        // deterministic sequential cross-wave reduction into LDS
        for (int k = 0; k < NW; ++k) {
            __syncthreads();
            if (wave == k) {
#pragma unroll
                for (int i = 0; i < BR; ++i) {
                    qacc[i][lane] += qa[i];
                    pacc[i][lane] += pa[i];
                }
            }
        }
        __syncthreads();
        // finalize: qhat = q^2 * (1 + 0.1*tanh(p))   (in place)
#pragma unroll
        for (int i = 0; i < (BR*RR)/BLOCK; ++i) {
            const int idx = tid + i*BLOCK;
            const float q = (&qacc[0][0])[idx];
            const float p = (&pacc[0][0])[idx];
            (&qacc[0][0])[idx] = q*q*(1.0f + 0.1f*tanhf(p));
        }
        __syncthreads();

        // ---------- Phase G: gamma = qhat@W ; v += d*dt*(-gamma*sing + force) ----------
        float g[BR][4];
#pragma unroll
        for (int i = 0; i < BR; ++i)
#pragma unroll
            for (int c = 0; c < 4; ++c) g[i][c] = 0.0f;
        {
            const float* __restrict__ Wp = Wm + tid;   // d = c*256 + tid, coalesced per wave
#pragma unroll 2
            for (int r = 0; r < RR; ++r) {
                const float w0v = Wp[r*DD];
                const float w1v = Wp[r*DD + 256];
                const float w2v = Wp[r*DD + 512];
                const float w3v = Wp[r*DD + 768];
                float q8[BR];
#pragma unroll
                for (int i = 0; i < BR; ++i) q8[i] = qacc[i][r];   // uniform b32
#pragma unroll
                for (int i = 0; i < BR; ++i) {
                    g[i][0] = fmaf(q8[i], w0v, g[i][0]);
                    g[i][1] = fmaf(q8[i], w1v, g[i][1]);
                    g[i][2] = fmaf(q8[i], w2v, g[i][2]);
                    g[i][3] = fmaf(q8[i], w3v, g[i][3]);
                }
            }
        }
#pragma unroll
        for (int i = 0; i < BR; ++i) {
            const float sg = sing[i];
            const float* __restrict__ fp = force + (row0 + i) * DD + tid;
#pragma unroll
            for (int c = 0; c < 4; ++c) {
                const float a = fmaf(-g[i][c], sg, fp[c*256]);     // -gamma*sing + force
                vs[i][c*256 + tid] = fmaf(ddtk, a, vs[i][c*256 + tid]);
            }
        }
        __syncthreads();
    };

    for (int s = 0; s < nsteps; ++s) {
        substep(c1, d1);   // x+=C1 dt v ; v+=D1 dt a
        substep(c2, d2);   // C2, D2
        substep(c2, d1);   // C3==C2, D3==D1
        // final drift: x += C4*dt*v  (C4 == C1)
#pragma unroll
        for (int i = 0; i < BR; ++i) {
            float4 xv = xs4[tid + i*BLOCK];
            const float4 vv = vs4[tid + i*BLOCK];
            xv.x = fmaf(c1, vv.x, xv.x);
            xv.y = fmaf(c1, vv.y, xv.y);
            xv.z = fmaf(c1, vv.z, xv.z);
            xv.w = fmaf(c1, vv.w, xv.w);
            xs4[tid + i*BLOCK] = xv;
        }
        __syncthreads();
    }

    // ---- write out: [x ; v] concatenated ----
    {
        float4* ox = (float4*)(out + row0 * DD);
        float4* ov = (float4*)(out + vout_off + row0 * DD);
#pragma unroll
        for (int i = 0; i < (BR*DD/4)/BLOCK; ++i) {
            ox[tid + i*BLOCK] = xs4[tid + i*BLOCK];
            ov[tid + i*BLOCK] = vs4[tid + i*BLOCK];
        }
    }
}

extern "C" void kernel_launch(void* const* d_in, const int* in_sizes, int n_in,
                              void* d_out, int out_size, void* d_ws, size_t ws_size,
                              hipStream_t stream) {
    const float* x  = (const float*)d_in[0];
    const float* v  = (const float*)d_in[1];
    const float* f  = (const float*)d_in[2];
    const float* U  = (const float*)d_in[3];
    const float* Wm = (const float*)d_in[4];
    const float* Vw = (const float*)d_in[5];
    const int* steps = (const int*)d_in[6];

    const int Btot = in_sizes[0] / DD;          // 8192
    const long vout_off = (long)Btot * DD;      // v follows x in d_out

    dim3 grid(Btot / BR), block(BLOCK);
    hipLaunchKernelGGL(yoshida_kernel, grid, block, 0, stream,
                       x, v, f, U, Wm, Vw, steps, (float*)d_out, vout_off);
}

// Round 2
// 651.886 us; speedup vs baseline: 1.5165x; 1.5165x over previous
//
#include <hip/hip_runtime.h>
#include <math.h>

#define DD 1024
#define RR 64
#define BRR 16      // batch rows per block
#define NTH 512     // 8 waves

typedef _Float16 f16x8 __attribute__((ext_vector_type(8)));
typedef float    f32x4 __attribute__((ext_vector_type(4)));

__device__ __forceinline__ f32x4 mfma16(f16x8 a, f16x8 b, f32x4 c) {
    return __builtin_amdgcn_mfma_f32_16x16x32_f16(a, b, c, 0, 0, 0);
}

// ---------------- prep: fragment + fp16-split U(x32), Vw(x32), W(x32) into d_ws ----------------
// frag layout (per matrix, per hi/lo): halfidx = ((kk*NT + nt)*64 + lane)*8 + e
//   element = M[k][col], k = kk*32 + (lane>>4)*8 + e, col = nt*16 + (lane&15)
__global__ void prep_kernel(const float* __restrict__ U, const float* __restrict__ Vw,
                            const float* __restrict__ Wm, _Float16* __restrict__ ws)
{
    int tid = blockIdx.x * blockDim.x + threadIdx.x;
    if (tid >= 3 * 65536) return;
    int m = tid >> 16;            // 0=U 1=Vw 2=W
    int r = tid & 65535;
    int l = (r >> 3) & 63;
    int e = r & 7;
    float val;
    if (m < 2) {
        int kk  = r >> 11;               // 0..31
        int nt  = (r >> 9) & 3;          // 0..3
        int k   = kk * 32 + (l >> 4) * 8 + e;   // 0..1023
        int col = nt * 16 + (l & 15);           // 0..63
        const float* src = (m == 0) ? U : Vw;
        val = src[k * RR + col] * 32.0f;
    } else {
        int kk  = r >> 15;               // 0..1
        int nt  = (r >> 9) & 63;         // 0..63
        int k   = kk * 32 + (l >> 4) * 8 + e;   // 0..63
        int col = nt * 16 + (l & 15);           // 0..1023
        val = Wm[k * DD + col] * 32.0f;
    }
    _Float16 h  = (_Float16)val;
    _Float16 lo = (_Float16)(val - (float)h);
    ws[m * 131072 + r]         = h;
    ws[m * 131072 + 65536 + r] = lo;
}

// ---------------- main fused integrator ----------------
__global__ __launch_bounds__(NTH, 2)
void yoshida_mfma(const float* __restrict__ x_in, const float* __restrict__ v_in,
                  const float* __restrict__ force, const int* __restrict__ steps_p,
                  const _Float16* __restrict__ ws, float* __restrict__ out, long vout_off,
                  float c1, float c2, float d1, float d2)
{
    __shared__ float xs[BRR * DD];        // fp32 state, XOR-swizzled rows
    __shared__ float vs[BRR * DD];
    __shared__ float q_s[BRR * RR];
    __shared__ float p_s[BRR * RR];
    __shared__ _Float16 qhA[2 * 2 * 64 * 8];   // [hi|lo][kk][lane][e]
    __shared__ float sing_s[BRR];
    __shared__ float xpart[8 * 16];

    const int tid = threadIdx.x;
    const int w = tid >> 6, l = tid & 63;
    const long row0 = (long)blockIdx.x * BRR;

    const _Float16* Uh = ws;
    const _Float16* Ul = ws + 65536;
    const _Float16* Vh = ws + 131072;
    const _Float16* Vl = ws + 196608;
    const _Float16* Wh = ws + 262144;
    const _Float16* Wl = ws + 327680;

    // ---- initial state load (coalesced global -> swizzled LDS) ----
    {
        const int row = tid >> 5, l5 = tid & 31;
        const unsigned swz = (row & 7) << 5;
        const float4* xg = (const float4*)(x_in + (row0 + row) * DD);
        const float4* vg = (const float4*)(v_in + (row0 + row) * DD);
        char* xb = (char*)xs + row * 4096;
        char* vb = (char*)vs + row * 4096;
#pragma unroll
        for (int c = 0; c < 8; ++c) {
            unsigned b = (unsigned)(l5 * 128 + c * 16);
            *(float4*)(xb + (b ^ swz)) = xg[l5 * 8 + c];
            *(float4*)(vb + (b ^ swz)) = vg[l5 * 8 + c];
        }
    }
    // ---- force preload in C-fragment layout (nt = w*8+i) ----
    float f_reg[8][4];
#pragma unroll
    for (int i = 0; i < 8; ++i) {
        int nt = w * 8 + i;
#pragma unroll
        for (int j = 0; j < 4; ++j) {
            int row = (l >> 4) * 4 + j;
            f_reg[i][j] = force[(row0 + row) * DD + nt * 16 + (l & 15)];
        }
    }
    const int nsteps = steps_p[0];
    __syncthreads();

    for (int s = 0; s < nsteps; ++s) {
        for (int sub = 0; sub < 3; ++sub) {
            const float cdt = (sub == 0) ? c1 : c2;
            const float ddt = (sub == 1) ? d2 : d1;

            // ---------- Phase A: drift x += cdt*v, row-norm partials, zero q/p ----------
            {
                const int row = tid & 15, piece = tid >> 4;   // LDS-friendly ownership
                const unsigned swz = (row & 7) << 5;
                char* xb = (char*)xs + row * 4096;
                char* vb = (char*)vs + row * 4096;
                float part = 0.0f;
#pragma unroll
                for (int c = 0; c < 4; ++c) {
                    unsigned b = ((unsigned)(piece * 4 + c) * 32) ^ swz;
                    float4* xp = (float4*)(xb + b);
                    const float4* vp = (const float4*)(vb + b);
                    float4 x0 = xp[0], x1 = xp[1];
                    float4 v0 = vp[0], v1 = vp[1];
                    x0.x = fmaf(cdt, v0.x, x0.x); x0.y = fmaf(cdt, v0.y, x0.y);
                    x0.z = fmaf(cdt, v0.z, x0.z); x0.w = fmaf(cdt, v0.w, x0.w);
                    x1.x = fmaf(cdt, v1.x, x1.x); x1.y = fmaf(cdt, v1.y, x1.y);
                    x1.z = fmaf(cdt, v1.z, x1.z); x1.w = fmaf(cdt, v1.w, x1.w);
                    xp[0] = x0; xp[1] = x1;
                    part = fmaf(x0.x, x0.x, part); part = fmaf(x0.y, x0.y, part);
                    part = fmaf(x0.z, x0.z, part); part = fmaf(x0.w, x0.w, part);
                    part = fmaf(x1.x, x1.x, part); part = fmaf(x1.y, x1.y, part);
                    part = fmaf(x1.z, x1.z, part); part = fmaf(x1.w, x1.w, part);
                }
                part += __shfl_xor(part, 16);
                part += __shfl_xor(part, 32);
                if (l < 16) xpart[w * 16 + row] = part;
                // zero q,p accumulators
                if (tid < 256)      ((float4*)q_s)[tid]       = (float4){0.f, 0.f, 0.f, 0.f};
                else                ((float4*)p_s)[tid - 256] = (float4){0.f, 0.f, 0.f, 0.f};
            }
            __syncthreads();

            // ---------- Phase B: Q = (v/16)@(32U), P = (x/16)@(32Vw); K-split, LDS-atomic reduce ----------
            {
                const int kq = w & 3;
                const bool isQ = (w < 4);
                const _Float16* Bh = isQ ? Uh : Vh;
                const _Float16* Bl = isQ ? Ul : Vl;
                const int arow = l & 15;
                const unsigned aswz = (arow & 7) << 5;
                const unsigned abase = (unsigned)(arow * 4096);
                f32x4 acc0 = 0, acc1 = 0, acc2 = 0, acc3 = 0;
#pragma unroll 2
                for (int ks = kq * 8; ks < kq * 8 + 8; ++ks) {
                    unsigned b = abase + (((unsigned)(ks * 128 + (l >> 4) * 32)) ^ aswz);
                    float4 a0, a1;
                    if (isQ) { const float4* ap = (const float4*)((const char*)vs + b); a0 = ap[0]; a1 = ap[1]; }
                    else     { const float4* ap = (const float4*)((const char*)xs + b); a0 = ap[0]; a1 = ap[1]; }
                    f16x8 ah, al;
                    {
                        float t;
                        t = a0.x * 0.0625f; ah[0] = (_Float16)t; al[0] = (_Float16)(t - (float)ah[0]);
                        t = a0.y * 0.0625f; ah[1] = (_Float16)t; al[1] = (_Float16)(t - (float)ah[1]);
                        t = a0.z * 0.0625f; ah[2] = (_Float16)t; al[2] = (_Float16)(t - (float)ah[2]);
                        t = a0.w * 0.0625f; ah[3] = (_Float16)t; al[3] = (_Float16)(t - (float)ah[3]);
                        t = a1.x * 0.0625f; ah[4] = (_Float16)t; al[4] = (_Float16)(t - (float)ah[4]);
                        t = a1.y * 0.0625f; ah[5] = (_Float16)t; al[5] = (_Float16)(t - (float)ah[5]);
                        t = a1.z * 0.0625f; ah[6] = (_Float16)t; al[6] = (_Float16)(t - (float)ah[6]);
                        t = a1.w * 0.0625f; ah[7] = (_Float16)t; al[7] = (_Float16)(t - (float)ah[7]);
                    }
                    const f16x8* B8h = ((const f16x8*)Bh) + ks * 256 + l;
                    const f16x8* B8l = ((const f16x8*)Bl) + ks * 256 + l;
                    f16x8 b0h = B8h[0],   b0l = B8l[0];
                    f16x8 b1h = B8h[64],  b1l = B8l[64];
                    f16x8 b2h = B8h[128], b2l = B8l[128];
                    f16x8 b3h = B8h[192], b3l = B8l[192];
                    acc0 = mfma16(ah, b0h, acc0); acc0 = mfma16(ah, b0l, acc0); acc0 = mfma16(al, b0h, acc0);
                    acc1 = mfma16(ah, b1h, acc1); acc1 = mfma16(ah, b1l, acc1); acc1 = mfma16(al, b1h, acc1);
                    acc2 = mfma16(ah, b2h, acc2); acc2 = mfma16(ah, b2l, acc2); acc2 = mfma16(al, b2h, acc2);
                    acc3 = mfma16(ah, b3h, acc3); acc3 = mfma16(al, b3h, acc3); acc3 = mfma16(ah, b3l, acc3);
                }
#pragma unroll
                for (int j = 0; j < 4; ++j) {
                    int row = (l >> 4) * 4 + j;
                    int base = row * RR + (l & 15);
                    if (isQ) {
                        atomicAdd(&q_s[base],      acc0[j]);
                        atomicAdd(&q_s[base + 16], acc1[j]);
                        atomicAdd(&q_s[base + 32], acc2[j]);
                        atomicAdd(&q_s[base + 48], acc3[j]);
                    } else {
                        atomicAdd(&p_s[base],      acc0[j]);
                        atomicAdd(&p_s[base + 16], acc1[j]);
                        atomicAdd(&p_s[base + 32], acc2[j]);
                        atomicAdd(&p_s[base + 48], acc3[j]);
                    }
                }
            }
            __syncthreads();

            // ---------- Phase C: qhat = 0.25*q'^2*(1+0.1*tanh(0.5*p')); split to G's A-frag; sing ----------
            for (int i = tid; i < BRR * RR; i += NTH) {
                float qv = q_s[i], pv = p_s[i];
                float qh = 0.25f * qv * qv * (1.0f + 0.1f * tanhf(0.5f * pv));
                _Float16 h  = (_Float16)qh;
                _Float16 lo = (_Float16)(qh - (float)h);
                int row = i >> 6, r = i & 63;
                int kk = r >> 5, g = (r >> 3) & 3, e = r & 7;
                int idx = (kk * 64 + row + 16 * g) * 8 + e;
                qhA[idx]        = h;
                qhA[1024 + idx] = lo;
            }
            if (tid < 16) {
                float xn2 = 0.0f;
#pragma unroll
                for (int k = 0; k < 8; ++k) xn2 += xpart[k * 16 + tid];
                sing_s[tid] = (1.0f + 20.0f * expf(-0.1f * xn2)) * (1.0f / 32.0f);
            }
            __syncthreads();

            // ---------- Phase D: G' = qhat@(32W); kick v += ddt*(-G'*sing/32 + force) ----------
            {
                const f16x8* qh8 = (const f16x8*)qhA;
                f16x8 A0h = qh8[l], A1h = qh8[64 + l];
                f16x8 A0l = qh8[128 + l], A1l = qh8[192 + l];
#pragma unroll
                for (int i = 0; i < 8; ++i) {
                    int nt = w * 8 + i;
                    const f16x8* W8h = ((const f16x8*)Wh) + nt * 64 + l;
                    const f16x8* W8l = ((const f16x8*)Wl) + nt * 64 + l;
                    f16x8 b0h = W8h[0], b0l = W8l[0];
                    f16x8 b1h = W8h[4096], b1l = W8l[4096];
                    f32x4 acc = 0;
                    acc = mfma16(A0h, b0h, acc); acc = mfma16(A0h, b0l, acc); acc = mfma16(A0l, b0h, acc);
                    acc = mfma16(A1h, b1h, acc); acc = mfma16(A1h, b1l, acc); acc = mfma16(A1l, b1h, acc);
#pragma unroll
                    for (int j = 0; j < 4; ++j) {
                        int row = (l >> 4) * 4 + j;
                        int col = nt * 16 + (l & 15);
                        float a = fmaf(-acc[j], sing_s[row], f_reg[i][j]);
                        unsigned b = (unsigned)(row * 4096 + col * 4) ^ ((unsigned)(row & 7) << 5);
                        float* pv = (float*)((char*)vs + b);
                        *pv = fmaf(ddt, a, *pv);
                    }
                }
            }
            __syncthreads();
        } // sub

        // ---------- bare drift: x += c1*v (C4 == C1) ----------
        {
            const int row = tid & 15, piece = tid >> 4;
            const unsigned swz = (row & 7) << 5;
            char* xb = (char*)xs + row * 4096;
            char* vb = (char*)vs + row * 4096;
#pragma unroll
            for (int c = 0; c < 4; ++c) {
                unsigned b = ((unsigned)(piece * 4 + c) * 32) ^ swz;
                float4* xp = (float4*)(xb + b);
                const float4* vp = (const float4*)(vb + b);
                float4 x0 = xp[0], x1 = xp[1];
                float4 v0 = vp[0], v1 = vp[1];
                x0.x = fmaf(c1, v0.x, x0.x); x0.y = fmaf(c1, v0.y, x0.y);
                x0.z = fmaf(c1, v0.z, x0.z); x0.w = fmaf(c1, v0.w, x0.w);
                x1.x = fmaf(c1, v1.x, x1.x); x1.y = fmaf(c1, v1.y, x1.y);
                x1.z = fmaf(c1, v1.z, x1.z); x1.w = fmaf(c1, v1.w, x1.w);
                xp[0] = x0; xp[1] = x1;
            }
        }
        __syncthreads();
    } // steps

    // ---------- output: [x ; v] ----------
    {
        const int row = tid >> 5, l5 = tid & 31;
        const unsigned swz = (row & 7) << 5;
        float4* ox = (float4*)(out + (row0 + row) * DD);
        float4* ov = (float4*)(out + vout_off + (row0 + row) * DD);
        const char* xb = (const char*)xs + row * 4096;
        const char* vb = (const char*)vs + row * 4096;
#pragma unroll
        for (int c = 0; c < 8; ++c) {
            unsigned b = (unsigned)(l5 * 128 + c * 16);
            ox[l5 * 8 + c] = *(const float4*)(xb + (b ^ swz));
            ov[l5 * 8 + c] = *(const float4*)(vb + (b ^ swz));
        }
    }
}

extern "C" void kernel_launch(void* const* d_in, const int* in_sizes, int n_in,
                              void* d_out, int out_size, void* d_ws, size_t ws_size,
                              hipStream_t stream) {
    (void)n_in; (void)out_size; (void)ws_size;
    const float* x  = (const float*)d_in[0];
    const float* v  = (const float*)d_in[1];
    const float* f  = (const float*)d_in[2];
    const float* U  = (const float*)d_in[3];
    const float* Wm = (const float*)d_in[4];
    const float* Vw = (const float*)d_in[5];
    const int* steps = (const int*)d_in[6];

    const int Btot = in_sizes[0] / DD;           // 8192
    const long vout_off = (long)Btot * DD;

    _Float16* ws = (_Float16*)d_ws;

    // match Python: W1 = 1/(2-2^(1/3)), W0 = -2^(1/3)/(2-2^(1/3)), dt = 0.01
    double cb = pow(2.0, 1.0 / 3.0);
    double den = 2.0 - cb;
    double w1 = 1.0 / den, w0 = -cb / den;
    double dt = 0.01 * 1.0;
    float c1 = (float)(w1 / 2.0 * dt);
    float c2 = (float)((w0 + w1) / 2.0 * dt);
    float d1 = (float)(w1 * dt);
    float d2 = (float)(w0 * dt);

    hipLaunchKernelGGL(prep_kernel, dim3((3 * 65536 + 255) / 256), dim3(256), 0, stream,
                       U, Vw, Wm, ws);
    hipLaunchKernelGGL(yoshida_mfma, dim3(Btot / BRR), dim3(NTH), 0, stream,
                       x, v, f, steps, (const _Float16*)ws, (float*)d_out, vout_off,
                       c1, c2, d1, d2);
}

// Round 3
// 576.893 us; speedup vs baseline: 1.7137x; 1.1300x over previous
//
#include <hip/hip_runtime.h>
#include <math.h>

#define DD 1024
#define RR 64

typedef _Float16 f16x8 __attribute__((ext_vector_type(8)));
typedef _Float16 h2    __attribute__((ext_vector_type(2)));
typedef float    f32x4 __attribute__((ext_vector_type(4)));

__device__ __forceinline__ f32x4 mfma16(f16x8 a, f16x8 b, f32x4 c) {
    return __builtin_amdgcn_mfma_f32_16x16x32_f16(a, b, c, 0, 0, 0);
}

// prep: hi-only fp16 fragments, matrices scaled x32.
// U  frags [kt0..31][Nt0..3][l][e]:  U[k][col], k=kt*32+(l>>4)*8+e, col=Nt*16+(l&15)
// Vw frags: same layout, at +65536
// Wt frags [Nt0..63][ktr0..1][l][e]: W[r][n],  n=Nt*16+(l&15), r=ktr*32+(l>>4)*8+e  (+131072)
__global__ void prep_kernel(const float* __restrict__ U, const float* __restrict__ Vw,
                            const float* __restrict__ Wm, _Float16* __restrict__ ws)
{
    int tid = blockIdx.x * blockDim.x + threadIdx.x;
    if (tid >= 3 * 65536) return;
    int m = tid >> 16;
    int r = tid & 65535;
    int l = (r >> 3) & 63;
    int e = r & 7;
    int tile = r >> 9;
    float val;
    if (m < 2) {
        int kt = tile >> 2, Nt = tile & 3;
        int k = kt * 32 + (l >> 4) * 8 + e;
        int col = Nt * 16 + (l & 15);
        val = (m == 0 ? U : Vw)[k * RR + col] * 32.0f;
    } else {
        int Nt = tile >> 1, ktr = tile & 1;
        int n = Nt * 16 + (l & 15);
        int rr = ktr * 32 + (l >> 4) * 8 + e;
        val = Wm[rr * DD + n] * 32.0f;
    }
    ws[m * 65536 + r] = (_Float16)val;
}

// 4 waves/block, 16 rows/block, wave w owns k (and n) in [w*256, w*256+256).
// State x,v in VGPRs in A-fragment layout: lane(m16,g) holds row m16, k = kt*32+g*8+e.
__global__ __launch_bounds__(256, 2)
void yoshida3(const float* __restrict__ x_in, const float* __restrict__ v_in,
              const float* __restrict__ force, const int* __restrict__ steps_p,
              const _Float16* __restrict__ ws, float* __restrict__ out, long vout_off,
              float c1, float c2, float d1, float d2)
{
    __shared__ float red_q[4 * 16 * 68];      // [wave][m][r] stride 68 (2-way max conflicts)
    __shared__ float red_p[4 * 16 * 68];
    __shared__ _Float16 qh_s[2 * 64 * 8];     // qhat^T B-frags (hi fp16)
    __shared__ float xn_s[4 * 16];
    __shared__ float sing_s[16];

    const int tid = threadIdx.x;
    const int w = tid >> 6, l = tid & 63;
    const int m16 = l & 15, g = l >> 4;
    const long row0 = (long)blockIdx.x * 16;

    const _Float16* __restrict__ Uf = ws;
    const _Float16* __restrict__ Vf = ws + 65536;
    const _Float16* __restrict__ Wf = ws + 131072;

    float xr[64], vr[64];
    h2 fh[32];                                 // force, fp16-hi, packed pairs

    {
        const float* xp = x_in + (row0 + m16) * DD + w * 256 + g * 8;
        const float* vp = v_in + (row0 + m16) * DD + w * 256 + g * 8;
        const float* fp = force + (row0 + m16) * DD + w * 256 + g * 8;
#pragma unroll
        for (int kt = 0; kt < 8; ++kt) {
            float4 a = *(const float4*)(xp + kt * 32);
            float4 b = *(const float4*)(xp + kt * 32 + 4);
            xr[kt*8+0]=a.x; xr[kt*8+1]=a.y; xr[kt*8+2]=a.z; xr[kt*8+3]=a.w;
            xr[kt*8+4]=b.x; xr[kt*8+5]=b.y; xr[kt*8+6]=b.z; xr[kt*8+7]=b.w;
            float4 c = *(const float4*)(vp + kt * 32);
            float4 d = *(const float4*)(vp + kt * 32 + 4);
            vr[kt*8+0]=c.x; vr[kt*8+1]=c.y; vr[kt*8+2]=c.z; vr[kt*8+3]=c.w;
            vr[kt*8+4]=d.x; vr[kt*8+5]=d.y; vr[kt*8+6]=d.z; vr[kt*8+7]=d.w;
            float4 e4 = *(const float4*)(fp + kt * 32);
            float4 e5 = *(const float4*)(fp + kt * 32 + 4);
            fh[kt*4+0] = (h2){(_Float16)e4.x, (_Float16)e4.y};
            fh[kt*4+1] = (h2){(_Float16)e4.z, (_Float16)e4.w};
            fh[kt*4+2] = (h2){(_Float16)e5.x, (_Float16)e5.y};
            fh[kt*4+3] = (h2){(_Float16)e5.z, (_Float16)e5.w};
        }
    }
    const int nsteps = steps_p[0];

    for (int s = 0; s < nsteps; ++s) {
#pragma unroll 1
        for (int sub = 0; sub < 3; ++sub) {
            const float cdt = (sub == 0) ? c1 : c2;
            const float ddt = (sub == 1) ? d2 : d1;

            // ---- drift x += cdt*v (registers) + ||x||^2 partials ----
            float part = 0.0f;
#pragma unroll
            for (int i = 0; i < 64; ++i) {
                float xn = fmaf(cdt, vr[i], xr[i]);
                xr[i] = xn;
                part = fmaf(xn, xn, part);
            }
            part += __shfl_xor(part, 16);
            part += __shfl_xor(part, 32);
            if (l < 16) xn_s[w * 16 + l] = part;

            // ---- Q = v @ U' over wave's k-quarter (A split hi/lo, B hi) ----
            {
                f32x4 q0 = {0,0,0,0}, q1 = {0,0,0,0}, q2 = {0,0,0,0}, q3 = {0,0,0,0};
#pragma unroll
                for (int kt = 0; kt < 8; ++kt) {
                    const f16x8* UB = (const f16x8*)Uf + ((w * 8 + kt) * 4) * 64 + l;
                    f16x8 b0 = UB[0], b1 = UB[64], b2 = UB[128], b3 = UB[192];
                    f16x8 ah, al;
#pragma unroll
                    for (int e = 0; e < 8; ++e) {
                        float t = vr[kt * 8 + e];
                        _Float16 h = (_Float16)t;
                        ah[e] = h;
                        al[e] = (_Float16)(t - (float)h);
                    }
                    q0 = mfma16(ah, b0, q0); q1 = mfma16(ah, b1, q1);
                    q2 = mfma16(ah, b2, q2); q3 = mfma16(ah, b3, q3);
                    q0 = mfma16(al, b0, q0); q1 = mfma16(al, b1, q1);
                    q2 = mfma16(al, b2, q2); q3 = mfma16(al, b3, q3);
                }
#pragma unroll
                for (int j = 0; j < 4; ++j) {
                    int base = w * 1088 + (g * 4 + j) * 68 + m16;
                    red_q[base]      = q0[j];
                    red_q[base + 16] = q1[j];
                    red_q[base + 32] = q2[j];
                    red_q[base + 48] = q3[j];
                }
            }
            // ---- P = x @ Vw' ----
            {
                f32x4 p0 = {0,0,0,0}, p1 = {0,0,0,0}, p2 = {0,0,0,0}, p3 = {0,0,0,0};
#pragma unroll
                for (int kt = 0; kt < 8; ++kt) {
                    const f16x8* VB = (const f16x8*)Vf + ((w * 8 + kt) * 4) * 64 + l;
                    f16x8 b0 = VB[0], b1 = VB[64], b2 = VB[128], b3 = VB[192];
                    f16x8 ah, al;
#pragma unroll
                    for (int e = 0; e < 8; ++e) {
                        float t = xr[kt * 8 + e];
                        _Float16 h = (_Float16)t;
                        ah[e] = h;
                        al[e] = (_Float16)(t - (float)h);
                    }
                    p0 = mfma16(ah, b0, p0); p1 = mfma16(ah, b1, p1);
                    p2 = mfma16(ah, b2, p2); p3 = mfma16(ah, b3, p3);
                    p0 = mfma16(al, b0, p0); p1 = mfma16(al, b1, p1);
                    p2 = mfma16(al, b2, p2); p3 = mfma16(al, b3, p3);
                }
#pragma unroll
                for (int j = 0; j < 4; ++j) {
                    int base = w * 1088 + (g * 4 + j) * 68 + m16;
                    red_p[base]      = p0[j];
                    red_p[base + 16] = p1[j];
                    red_p[base + 32] = p2[j];
                    red_p[base + 48] = p3[j];
                }
            }
            __syncthreads();   // barrier A

            // ---- reduce: qhat = (q/32)^2*(1+0.1*tanh(p/32)); write qhat^T B-frags; sing ----
            {
                const int m = tid & 15, r0 = (tid >> 4) * 4;
                float qa0=0,qa1=0,qa2=0,qa3=0, pa0=0,pa1=0,pa2=0,pa3=0;
#pragma unroll
                for (int w4 = 0; w4 < 4; ++w4) {
                    float4 a = *(const float4*)&red_q[w4 * 1088 + m * 68 + r0];
                    qa0 += a.x; qa1 += a.y; qa2 += a.z; qa3 += a.w;
                    float4 b = *(const float4*)&red_p[w4 * 1088 + m * 68 + r0];
                    pa0 += b.x; pa1 += b.y; pa2 += b.z; pa3 += b.w;
                }
                float qr, pr, qh0, qh1, qh2, qh3;
                qr = qa0 * 0.03125f; pr = pa0 * 0.03125f; qh0 = qr*qr*(1.0f + 0.1f*tanhf(pr));
                qr = qa1 * 0.03125f; pr = pa1 * 0.03125f; qh1 = qr*qr*(1.0f + 0.1f*tanhf(pr));
                qr = qa2 * 0.03125f; pr = pa2 * 0.03125f; qh2 = qr*qr*(1.0f + 0.1f*tanhf(pr));
                qr = qa3 * 0.03125f; pr = pa3 * 0.03125f; qh3 = qr*qr*(1.0f + 0.1f*tanhf(pr));
                int kt = r0 >> 5, gp = (r0 >> 3) & 3, e0 = r0 & 7;
                h2* dst = (h2*)&qh_s[(kt * 64 + gp * 16 + m) * 8 + e0];
                dst[0] = (h2){(_Float16)qh0, (_Float16)qh1};
                dst[1] = (h2){(_Float16)qh2, (_Float16)qh3};
                if (tid < 16) {
                    float xn2 = xn_s[tid] + xn_s[16 + tid] + xn_s[32 + tid] + xn_s[48 + tid];
                    sing_s[tid] = (1.0f + 20.0f * expf(-0.1f * xn2)) * 0.03125f;
                }
            }
            __syncthreads();   // barrier B

            // ---- G^T = Wt' * qhat^T over wave's n-quarter; kick v ----
            {
                const f16x8 qb0 = *(const f16x8*)&qh_s[l * 8];
                const f16x8 qb1 = *(const f16x8*)&qh_s[(64 + l) * 8];
                const float ss = sing_s[m16];
#pragma unroll
                for (int kti = 0; kti < 8; ++kti) {
                    const int Nt0 = w * 16 + kti * 2;
                    const f16x8* WA = (const f16x8*)Wf + Nt0 * 128 + l;
                    f16x8 w00 = WA[0], w01 = WA[64], w10 = WA[128], w11 = WA[192];
                    f32x4 accA = {0,0,0,0}, accB = {0,0,0,0};
                    accA = mfma16(w00, qb0, accA);
                    accA = mfma16(w01, qb1, accA);
                    accB = mfma16(w10, qb0, accB);
                    accB = mfma16(w11, qb1, accB);
                    // permute C-frag (n' = g*4+j) into state layout (n = g*8+e), same m-lane set
#pragma unroll
                    for (int e = 0; e < 8; ++e) {
                        int src = m16 + ((((g & 1) << 1) + (e >> 2)) << 4);
                        float t0 = __shfl(accA[e & 3], src);
                        float t1 = __shfl(accB[e & 3], src);
                        float gval = (g & 2) ? t1 : t0;
                        float fval = (float)fh[kti * 4 + (e >> 1)][e & 1];
                        vr[kti * 8 + e] = fmaf(ddt, fmaf(-gval, ss, fval), vr[kti * 8 + e]);
                    }
                }
            }
        } // sub

        // ---- final drift x += c1*v (C4 == C1), pure registers ----
#pragma unroll
        for (int i = 0; i < 64; ++i) xr[i] = fmaf(c1, vr[i], xr[i]);
    } // steps

    // ---- output [x ; v] ----
    {
        float* ox = out + (row0 + m16) * DD + w * 256 + g * 8;
        float* ov = out + vout_off + (row0 + m16) * DD + w * 256 + g * 8;
#pragma unroll
        for (int kt = 0; kt < 8; ++kt) {
            *(float4*)(ox + kt*32)     = (float4){xr[kt*8+0], xr[kt*8+1], xr[kt*8+2], xr[kt*8+3]};
            *(float4*)(ox + kt*32 + 4) = (float4){xr[kt*8+4], xr[kt*8+5], xr[kt*8+6], xr[kt*8+7]};
            *(float4*)(ov + kt*32)     = (float4){vr[kt*8+0], vr[kt*8+1], vr[kt*8+2], vr[kt*8+3]};
            *(float4*)(ov + kt*32 + 4) = (float4){vr[kt*8+4], vr[kt*8+5], vr[kt*8+6], vr[kt*8+7]};
        }
    }
}

extern "C" void kernel_launch(void* const* d_in, const int* in_sizes, int n_in,
                              void* d_out, int out_size, void* d_ws, size_t ws_size,
                              hipStream_t stream) {
    (void)n_in; (void)out_size; (void)ws_size;
    const float* x  = (const float*)d_in[0];
    const float* v  = (const float*)d_in[1];
    const float* f  = (const float*)d_in[2];
    const float* U  = (const float*)d_in[3];
    const float* Wm = (const float*)d_in[4];
    const float* Vw = (const float*)d_in[5];
    const int* steps = (const int*)d_in[6];

    const int Btot = in_sizes[0] / DD;           // 8192
    const long vout_off = (long)Btot * DD;

    double cb = pow(2.0, 1.0 / 3.0);
    double den = 2.0 - cb;
    double w1 = 1.0 / den, w0 = -cb / den;
    double dt = 0.01 * 1.0;
    float c1 = (float)(w1 / 2.0 * dt);
    float c2 = (float)((w0 + w1) / 2.0 * dt);
    float d1 = (float)(w1 * dt);
    float d2 = (float)(w0 * dt);

    hipLaunchKernelGGL(prep_kernel, dim3((3 * 65536 + 255) / 256), dim3(256), 0, stream,
                       U, Vw, Wm, (_Float16*)d_ws);
    hipLaunchKernelGGL(yoshida3, dim3(Btot / 16), dim3(256), 0, stream,
                       x, v, f, steps, (const _Float16*)d_ws, (float*)d_out, vout_off,
                       c1, c2, d1, d2);
}